// Round 8
// baseline (129.372 us; speedup 1.0000x reference)
//
#include <hip/hip_runtime.h>
#include <hip/hip_bf16.h>

constexpr int CH = 128;    // channels
constexpr int NPOS = 4096; // h*w
constexpr int NB = 4;      // batch
constexpr int SPLITS = 8;  // split-K factor for flash attention

typedef __bf16 bf16x8 __attribute__((ext_vector_type(8)));
typedef float f32x2 __attribute__((ext_vector_type(2)));
typedef float f32x16 __attribute__((ext_vector_type(16)));

// (1/sqrt(128)) * log2(e): fold softmax scale into Qb so MFMA emits exp2-domain
constexpr float CSC = 0.08838834764831845f * 1.4426950408889634f;

// Frag-native layout for Q/K (mfma_32x32x16 A/B operand order):
// [b][t32 = pos>>5][kf = c>>4][lane][j]; lane = (pos&31) + 32*((c>>3)&1),
// j = c&7. One (t32,kf) chunk = contiguous 1 KB; one t32 tile = 8 KB.

// Barrier that waits ONLY LDS ops (lgkmcnt) — leaves global loads in flight.
// (Reg-transit staging means barrier correctness needs no vmcnt drain: the
// compiler inserts a precise vmcnt(k) before the ds_write that consumes the
// loaded regs.)
#define LGKM_BARRIER() \
  asm volatile("s_waitcnt lgkmcnt(0)\n\ts_barrier" ::: "memory")

// ---------------------------------------------------------------------------
// Fuse kernel: Wqk = Wk @ Wq, bqk = Wk@bq + bk; bf16 copies of Wq, Wqk.
// ---------------------------------------------------------------------------
__global__ __launch_bounds__(128) void fuse_w_kernel(
    const float* __restrict__ Wq, const float* __restrict__ bq,
    const float* __restrict__ Wk, const float* __restrict__ bk,
    __bf16* __restrict__ Wqb, __bf16* __restrict__ Wqkb,
    float* __restrict__ bqk) {
  __shared__ float red[CH];
  const int o = blockIdx.x;
  const int i = threadIdx.x;
  float acc = 0.f;
#pragma unroll 8
  for (int m = 0; m < CH; m++) acc += Wk[o * CH + m] * Wq[m * CH + i];
  Wqkb[o * CH + i] = (__bf16)acc;
  Wqb[o * CH + i] = (__bf16)Wq[o * CH + i];
  red[i] = Wk[o * CH + i] * bq[i];
  __syncthreads();
  if (i == 0) {
    float s = 0.f;
    for (int m = 0; m < CH; m++) s += red[m];
    bqk[o] = s + bk[o];
  }
}

// ---------------------------------------------------------------------------
// Projection via mfma_32x32x16_bf16, one wave per (32-pos tile, z) pair,
// frag-native output layout. z-split doubles wave parallelism (latency-bound
// kernel); A re-load for z=1 is L2/L3-resident. XCD-affinity on batch.
// ---------------------------------------------------------------------------
__global__ __launch_bounds__(64) void proj_kernel(
    const float* __restrict__ feature0, const __bf16* __restrict__ Wqb,
    const float* __restrict__ bq, const __bf16* __restrict__ Wqkb,
    const float* __restrict__ bqk, __bf16* __restrict__ Qf,
    __bf16* __restrict__ Kf) {
  const int bid = blockIdx.x;  // 1024 blocks
  const int b = (bid >> 1) & 3;
  const int uz = (bid >> 3) * 2 + (bid & 1);  // 0..255 per batch
  const int u = uz >> 1, z = uz & 1;
  const int lane = threadIdx.x;
  const int half = lane >> 5, l31 = lane & 31;
  const int pos = u * 32 + l31;

  bf16x8 A[8];
#pragma unroll
  for (int ks = 0; ks < 8; ks++) {
    float v[8];
#pragma unroll
    for (int j = 0; j < 8; j++)
      v[j] = feature0[(size_t)(b * CH + ks * 16 + half * 8 + j) * NPOS + pos];
#pragma unroll
    for (int j = 0; j < 8; j++) A[ks][j] = (__bf16)v[j];
  }

  const __bf16* W = z ? Wqkb : Wqb;
  const float* bias = z ? bqk : bq;
  __bf16* Out = z ? Kf : Qf;
  const float scale = z ? 1.0f : CSC;
#pragma unroll
  for (int n = 0; n < 4; n++) {
    const int co = n * 32 + l31;
    const bf16x8* Bp = (const bf16x8*)(W + co * CH + half * 8);
    f32x16 c = {0.f, 0.f, 0.f, 0.f, 0.f, 0.f, 0.f, 0.f,
                0.f, 0.f, 0.f, 0.f, 0.f, 0.f, 0.f, 0.f};
#pragma unroll
    for (int ks = 0; ks < 8; ks++)
      c = __builtin_amdgcn_mfma_f32_32x32x16_bf16(A[ks], Bp[ks * 2], c, 0, 0,
                                                  0);
    const float bv = bias[co];
    const int kf = n * 2 + (l31 >> 4);
    const int lanebit = (l31 >> 3) & 1;
    const int j = l31 & 7;
#pragma unroll
    for (int r = 0; r < 16; r++) {
      int roff = (r & 3) + 8 * (r >> 2) + 4 * half;  // pos offset in tile
      Out[((((size_t)(b * (NPOS / 32) + u)) * 8 + kf) * 64 +
           (roff + 32 * lanebit)) * 8 + j] = (__bf16)((c[r] + bv) * scale);
    }
  }
}

// ---------------------------------------------------------------------------
// Flash attention, split-K, no running max (scores exp2-domain bounded;
// verified R1-R7). mfma_32x32x16_bf16: wave = 32 q rows, block = 128 q rows.
// 64-key tiles (16 KB) shared across the 4 waves via LDS, double-buffered.
// Staging is global->VGPR->ds_write (reg transit): compiler emits a PRECISE
// vmcnt before the ds_write only; the per-tile barrier is raw
// "s_waitcnt lgkmcnt(0); s_barrier" (no vmcnt drain) so tile t+2's global
// loads stay in flight across it. One barrier per tile (2-buffer parity:
// the buffer written at iter t was last read at iter t-1, fenced by lgkm).
// ---------------------------------------------------------------------------
__global__ __launch_bounds__(256, 3) void attn_kernel(
    const __bf16* __restrict__ Qf, const __bf16* __restrict__ Kf,
    const float* __restrict__ flow, float* __restrict__ part) {
  __shared__ __bf16 Klds[2][8192];  // 2 x 16 KB (64 keys x 128 c each)
  __shared__ float flds[2 * 512];   // split's flow values
  __shared__ float red[128 * 3];

  const int bid = blockIdx.x;  // 1024 blocks
  const int b = (bid >> 1) & 3;
  const int u = (bid >> 3) * 2 + (bid & 1);  // 0..255 per batch
  const int split = u >> 5;                  // 8 splits
  const int qg = u & 31;                     // 32 q-groups of 128 rows

  const int tid = threadIdx.x;
  const int wave = tid >> 6, lane = tid & 63;
  const int half = lane >> 5, l31 = lane & 31;
  const int kbase = split * (NPOS / SPLITS);  // 512 keys per split
  constexpr int NT = 8;                       // 8 tiles of 64 keys

  // global K base for this (b, split): 8 contiguous 16 KB tiles
  const __bf16* Ktb =
      Kf + ((size_t)(b * (NPOS / 32) + (kbase >> 5))) * 4096;

  uint4 g[4];  // transit regs: 16 KB / 256 thr = 4 x 16 B per thread
  auto load_tile = [&](int t) {
    const uint4* gp = (const uint4*)(Ktb + (size_t)t * 8192);
#pragma unroll
    for (int i = 0; i < 4; i++) g[i] = gp[tid + i * 256];
  };
  auto write_tile = [&](int buf) {
    uint4* lp = (uint4*)&Klds[buf][0];
#pragma unroll
    for (int i = 0; i < 4; i++) lp[tid + i * 256] = g[i];
  };

  load_tile(0);

  // stage flow for this split into LDS (one-time)
  {
    const float* fl0 = flow + (size_t)(b * 2 + 0) * NPOS + kbase;
    const float* fl1 = flow + (size_t)(b * 2 + 1) * NPOS + kbase;
    for (int i = tid; i < 512; i += 256) {
      flds[i] = fl0[i];
      flds[512 + i] = fl1[i];
    }
  }

  // Q fragments: wave's 32 q rows = tile qt (CSC pre-folded)
  const int qt = qg * 4 + wave;  // 0..127
  bf16x8 qf[8];
  {
    const bf16x8* Qp =
        (const bf16x8*)Qf + ((size_t)(b * (NPOS / 32) + qt) * 8) * 64 + lane;
#pragma unroll
    for (int kf = 0; kf < 8; kf++) qf[kf] = Qp[kf * 64];
  }

  write_tile(0);  // compiler waits g(tile0) precisely here
  load_tile(1);

  float ls[16];
  f32x2 av[16];
#pragma unroll
  for (int r = 0; r < 16; r++) {
    ls[r] = 0.f;
    av[r] = f32x2{0.f, 0.f};
  }

  for (int t = 0; t < NT; t++) {
    LGKM_BARRIER();  // Klds[t&1] visible; buf[(t+1)&1] reads (iter t-1) done
    if (t + 1 < NT) {
      write_tile((t + 1) & 1);          // consumes g = tile t+1
      if (t + 2 < NT) load_tile(t + 2); // refill g; in flight across barrier
    }

    const __bf16* kb = &Klds[t & 1][0];
    f32x16 cA = {0.f, 0.f, 0.f, 0.f, 0.f, 0.f, 0.f, 0.f,
                 0.f, 0.f, 0.f, 0.f, 0.f, 0.f, 0.f, 0.f};
    f32x16 cB = cA;
#pragma unroll
    for (int kf = 0; kf < 8; kf++) {
      bf16x8 fA = *(const bf16x8*)(kb + kf * 512 + lane * 8);
      cA = __builtin_amdgcn_mfma_f32_32x32x16_bf16(qf[kf], fA, cA, 0, 0, 0);
    }
#pragma unroll
    for (int kf = 0; kf < 8; kf++) {
      bf16x8 fB = *(const bf16x8*)(kb + 4096 + kf * 512 + lane * 8);
      cB = __builtin_amdgcn_mfma_f32_32x32x16_bf16(qf[kf], fB, cB, 0, 0, 0);
    }

    const f32x2 vA = {flds[t * 64 + l31], flds[512 + t * 64 + l31]};
    const f32x2 vB = {flds[t * 64 + 32 + l31], flds[512 + t * 64 + 32 + l31]};
#pragma unroll
    for (int r = 0; r < 16; r++) {
      float pA = __builtin_amdgcn_exp2f(cA[r]);
      float pB = __builtin_amdgcn_exp2f(cB[r]);
      ls[r] += pA + pB;
      av[r] += f32x2{pA, pA} * vA + f32x2{pB, pB} * vB;
    }
  }

  // reduce across the 32 key-lanes (butterfly stays within each 32-lane half)
#pragma unroll
  for (int r = 0; r < 16; r++) {
#pragma unroll
    for (int st = 1; st < 32; st <<= 1) {
      ls[r] += __shfl_xor(ls[r], st, 64);
      av[r][0] += __shfl_xor(av[r][0], st, 64);
      av[r][1] += __shfl_xor(av[r][1], st, 64);
    }
  }
  if (l31 == 0) {
#pragma unroll
    for (int r = 0; r < 16; r++) {
      int ql = wave * 32 + (r & 3) + 8 * (r >> 2) + 4 * half;
      red[ql * 3 + 0] = ls[r];
      red[ql * 3 + 1] = av[r][0];
      red[ql * 3 + 2] = av[r][1];
    }
  }
  __syncthreads();
  for (int idx = tid; idx < 128 * 3; idx += 256) {
    int plane = idx / 128, ql = idx % 128;
    part[((size_t)(plane * SPLITS + split) * NB + b) * NPOS + qg * 128 + ql] =
        red[ql * 3 + plane];
  }
}

// ---------------------------------------------------------------------------
// Combine: sum split partials per plane, normalize, write out[b][2][n].
// ---------------------------------------------------------------------------
__global__ __launch_bounds__(256) void combine_kernel(
    const float* __restrict__ part, float* __restrict__ out) {
  int t = blockIdx.x * 256 + threadIdx.x;  // 0 .. NB*NPOS-1
  int b = t >> 12, q = t & (NPOS - 1);
  float l = 0.f, x = 0.f, y = 0.f;
#pragma unroll
  for (int s = 0; s < SPLITS; s++) {
    l += part[((size_t)(0 * SPLITS + s) * NB + b) * NPOS + q];
    x += part[((size_t)(1 * SPLITS + s) * NB + b) * NPOS + q];
    y += part[((size_t)(2 * SPLITS + s) * NB + b) * NPOS + q];
  }
  float inv = 1.0f / l;
  out[(size_t)(b * 2 + 0) * NPOS + q] = x * inv;
  out[(size_t)(b * 2 + 1) * NPOS + q] = y * inv;
}

extern "C" void kernel_launch(void* const* d_in, const int* in_sizes, int n_in,
                              void* d_out, int out_size, void* d_ws,
                              size_t ws_size, hipStream_t stream) {
  const float* feature0 = (const float*)d_in[0];
  const float* flow = (const float*)d_in[1];
  const float* Wq = (const float*)d_in[2];
  const float* bq = (const float*)d_in[3];
  const float* Wk = (const float*)d_in[4];
  const float* bk = (const float*)d_in[5];
  float* out = (float*)d_out;

  char* ws = (char*)d_ws;
  __bf16* Qf = (__bf16*)ws;                                 // 4 MB
  __bf16* Kf = (__bf16*)(ws + (4 << 20));                   // 4 MB
  __bf16* Wqb = (__bf16*)(ws + (8 << 20));                  // 32 KB
  __bf16* Wqkb = (__bf16*)(ws + (8 << 20) + (32 << 10));    // 32 KB
  float* bqk = (float*)(ws + (8 << 20) + (64 << 10));       // 512 B
  float* part = (float*)(ws + (8 << 20) + (128 << 10));     // 1.5 MB

  fuse_w_kernel<<<dim3(CH), 128, 0, stream>>>(Wq, bq, Wk, bk, Wqb, Wqkb, bqk);
  proj_kernel<<<dim3(1024), 64, 0, stream>>>(feature0, Wqb, bq, Wqkb, bqk, Qf,
                                             Kf);
  attn_kernel<<<dim3(1024), 256, 0, stream>>>(Qf, Kf, flow, part);
  combine_kernel<<<dim3(NB * NPOS / 256), 256, 0, stream>>>(part, out);
}